// Round 13
// baseline (102.084 us; speedup 1.0000x reference)
//
#include <hip/hip_runtime.h>
#include <hip/hip_bf16.h>

// RNN cell: out[B,N] = tanh( concat(x,hidden)[B,K] @ W^T[K,N] + b[N] )
// M=16384, N=1024, K=2048, fp32 in/out.
// Pass 1: fp32->bf16 cvt+concat into ws.
// Pass 2 (r13): 256x256 whole-tile GEMM, ONE raw barrier per K-tile.
//   - stage(t+1) issued at TOP of tile t (8 global_load_lds, dbuf)
//   - compute tile t: 24 swizzled ds_read_b128 + 64 MFMA, NO fences ->
//     compiler's fine-grained lgkmcnt(N) interleaves LDS pipe with MFMA pipe
//     (r9/r10/r12 showed the 8-phase barrier lockstep serializes them:
//     1738 cyc/phase vs ~900 content; this removes the lockstep)
//   - vmcnt(0)+s_barrier at tile END only: drain point ~2900 cyc after
//     issue -> stage latency fully hidden (r5 drained right after issue)
// XCD map (r13): 4 blocks sharing an A-panel -> same XCD (A L2-local);
//   cross-XCD (L3) traffic 8 MB -> 3 MB per K-tile.

typedef __bf16 bf16_t;
typedef __bf16 bf16x8 __attribute__((ext_vector_type(8)));
typedef float  f32x4  __attribute__((ext_vector_type(4)));

#define M_GLOBAL 16384
#define N_GLOBAL 1024
#define K_GLOBAL 2048
#define IN_STRIDE 1024
#define NT 32

__device__ __forceinline__ float fast_tanh(float v) {
    float e = __expf(2.0f * v);
    return 1.0f - 2.0f * __builtin_amdgcn_rcpf(e + 1.0f);
}

// ---------------------------------------------------------------------------
// Pass 1: cvt + concat (~6.4 TB/s; L3-warm on replay).
// ---------------------------------------------------------------------------
#define XH_UNITS ((long long)M_GLOBAL * K_GLOBAL / 8)
#define W_UNITS  ((long long)N_GLOBAL * K_GLOBAL / 8)

__global__ __launch_bounds__(256)
void cvt_pass(const float* __restrict__ x, const float* __restrict__ h,
              const float* __restrict__ W,
              bf16_t* __restrict__ XHb, bf16_t* __restrict__ Wb)
{
    const long long total = XH_UNITS + W_UNITS;
    for (long long u = (long long)blockIdx.x * 256 + threadIdx.x; u < total;
         u += (long long)gridDim.x * 256) {
        const float* src;
        bf16_t* dst;
        if (u < XH_UNITS) {
            const long long e = u * 8;
            const int row = (int)(e >> 11);
            const int col = (int)(e & 2047);
            src = (col < 1024) ? (x + (long long)row * IN_STRIDE + col)
                               : (h + (long long)row * IN_STRIDE + (col - 1024));
            dst = XHb + e;
        } else {
            const long long e = (u - XH_UNITS) * 8;
            src = W + e;
            dst = Wb + e;
        }
        const float4 v0 = *(const float4*)src;
        const float4 v1 = *(const float4*)(src + 4);
        bf16x8 o;
        o[0] = (bf16_t)v0.x; o[1] = (bf16_t)v0.y;
        o[2] = (bf16_t)v0.z; o[3] = (bf16_t)v0.w;
        o[4] = (bf16_t)v1.x; o[5] = (bf16_t)v1.y;
        o[6] = (bf16_t)v1.z; o[7] = (bf16_t)v1.w;
        *(bf16x8*)dst = o;
    }
}

// ---------------------------------------------------------------------------
// Pass 2: whole-tile GEMM. 512 threads = 8 waves (2M x 4N), 128x64 out/wave.
// BK=64. LDS: 2 dbuf x {A0,A1,B0,B1} 128x64 halves = 128 KB (1 block/CU).
// Swizzle (0 conflicts, verified r7/r9/r12): slot s of row r holds k-slot
// s^(r&7); applied on global SOURCE (gload_lds writes linearly) + ds_read.
//
// Race audit:
//  RAW (stage->read, cross-wave): stage(t+1) issued top of t; VM0 at end of
//    t drains each wave's own loads; s_barrier after the VM0 means ALL waves
//    passed their VM0 -> whole tile t+1 resident before any read of t+1.
//  WAR (read->stage): stage(t+1) targets buf (t+1)&1, last read in tile t-1.
//    A wave's reads complete before its MFMAs issue; MFMAs issue before the
//    wave reaches BAR(end of t-1); stage(t+1) is issued after that BAR.
// ---------------------------------------------------------------------------
__device__ __forceinline__ void gload_lds16(const bf16_t* g, bf16_t* l) {
    __builtin_amdgcn_global_load_lds(
        (const __attribute__((address_space(1))) void*)g,
        (__attribute__((address_space(3))) void*)l, 16, 0, 0);
}

__global__ __launch_bounds__(512, 2)
void gemm_wt(const bf16_t* __restrict__ XHb, const bf16_t* __restrict__ Wb,
             const float* __restrict__ bias, float* __restrict__ out)
{
    __shared__ __align__(16) bf16_t lds[2 * 32768];   // 128 KB

    const int tid = threadIdx.x;
    // XCD map: dispatch round-robins bid&7 across XCDs. The 4 blocks sharing
    // a bm (A-panel) get the same xcd -> A is fetched into ONE L2 and hit 4x;
    // each XCD sees all 4 bn-panels (B unique = 128 KB/tile, L2-resident).
    const int x = blockIdx.x & 7;
    const int g = blockIdx.x >> 3;
    const int bm = (x * 8 + (g & 7)) * 256;
    const int bn = (g >> 3) * 256;

    const int lane = tid & 63;
    const int wid  = tid >> 6;
    const int wm = wid >> 2;          // 0..1 (M half)
    const int wn = wid & 3;           // 0..3 (N quarter)
    const int lr = lane & 15;
    const int lk = lane >> 4;
    const int s7 = lr & 7;

    // staging: each wave stages 2 chunks of 8 rows per 128-row half; lane
    // covers row srow, source col pre-swizzled (linear LDS dest, rule 21).
    const int srow = lane >> 3;
    const int scol = ((lane & 7) ^ srow) * 8;
    const int c0   = wid * 2;
    const bf16_t* aS = XHb + (size_t)(bm + c0 * 8 + srow) * K_GLOBAL + scol;
    const bf16_t* bS = Wb  + (size_t)(bn + c0 * 8 + srow) * K_GLOBAL + scol;

    // frag-read bases (elems): parts A0,A1,B0,B1 at part*8192 within dbuf.
    const int aRd = wm * 8192 + lr * 64;
    const int bRd = (2 + (wn >> 1)) * 8192 + ((wn & 1) * 64 + lr) * 64;

    f32x4 acc[8][4];
#pragma unroll
    for (int i = 0; i < 8; ++i)
#pragma unroll
        for (int j = 0; j < 4; ++j)
            acc[i][j] = (f32x4){0.f, 0.f, 0.f, 0.f};

    // full-tile stage: 4 parts x 2 chunk-loads per wave (8 gloads/thread)
#define STAGE_FULL(T, D) {                                                    \
    _Pragma("unroll")                                                         \
    for (int p_ = 0; p_ < 4; ++p_) {                                          \
        const bf16_t* g_ = ((p_ < 2) ? aS : bS)                               \
            + (size_t)((p_ & 1) * 128) * K_GLOBAL + (T) * 64;                 \
        bf16_t* l_ = lds + (D) * 32768 + p_ * 8192 + c0 * 512;                \
        gload_lds16(g_, l_);                                                  \
        gload_lds16(g_ + (size_t)8 * K_GLOBAL, l_ + 512);                     \
    }                                                                         \
}

#define BAR() { asm volatile("" ::: "memory");                                \
                __builtin_amdgcn_s_barrier();                                 \
                asm volatile("" ::: "memory"); }
#define VM0() asm volatile("s_waitcnt vmcnt(0)" ::: "memory")

    // prologue: stage T0 -> dbuf0
    STAGE_FULL(0, 0);
    VM0();
    BAR();

    for (int t = 0; t < NT; ++t) {
        const int dbo = (t & 1) * 32768;

        // issue next tile's stage at the TOP: drained ~2900 cyc later at the
        // end-of-tile VM0 -> latency fully hidden under this tile's compute.
        if (t + 1 < NT) STAGE_FULL(t + 1, (t + 1) & 1);

        // whole-tile compute: no fences -- compiler interleaves the 24
        // ds_read_b128 with the 64 MFMAs via fine-grained lgkmcnt(N).
        __builtin_amdgcn_s_setprio(1);
#pragma unroll
        for (int kk = 0; kk < 2; ++kk) {
            const int sl = ((kk * 4 + lk) ^ s7) * 8;
            bf16x8 bq[4];
#pragma unroll
            for (int nf = 0; nf < 4; ++nf)
                bq[nf] = *(const bf16x8*)(lds + dbo + bRd + nf * 1024 + sl);
#pragma unroll
            for (int mf = 0; mf < 8; ++mf) {
                bf16x8 af = *(const bf16x8*)(lds + dbo + aRd + mf * 1024 + sl);
#pragma unroll
                for (int nf = 0; nf < 4; ++nf)
                    acc[mf][nf] = __builtin_amdgcn_mfma_f32_16x16x32_bf16(
                        af, bq[nf], acc[mf][nf], 0, 0, 0);
            }
        }
        __builtin_amdgcn_s_setprio(0);

        if (t + 1 < NT) { VM0(); BAR(); }
    }

#undef STAGE_FULL
#undef BAR
#undef VM0

    // ---- epilogue: bias + tanh, fp32 store.
    // C/D layout: col = lane&15, row = (lane>>4)*4 + reg (verified r1-r12).
    float bv[4];
#pragma unroll
    for (int nf = 0; nf < 4; ++nf)
        bv[nf] = bias[bn + wn * 64 + nf * 16 + lr];
#pragma unroll
    for (int mf = 0; mf < 8; ++mf) {
#pragma unroll
        for (int nf = 0; nf < 4; ++nf) {
            const int col = bn + wn * 64 + nf * 16 + lr;
#pragma unroll
            for (int r = 0; r < 4; ++r) {
                const int row = bm + wm * 128 + mf * 16 + lk * 4 + r;
                out[(size_t)row * N_GLOBAL + col] = fast_tanh(acc[mf][nf][r] + bv[nf]);
            }
        }
    }
}

// ---------------------------------------------------------------------------
// Fallback (ws too small): round-3 verified fused kernel (~169 us).
// ---------------------------------------------------------------------------
#define FNT 32
__global__ __launch_bounds__(256, 2)
void rnncell_fused(const float* __restrict__ x, const float* __restrict__ h,
                   const float* __restrict__ W, const float* __restrict__ bias,
                   float* __restrict__ out)
{
    __shared__ __align__(16) bf16_t As[2][128 * 64];
    __shared__ __align__(16) bf16_t Bs[2][128 * 64];

    const int tid = threadIdx.x;
    const int bid = blockIdx.x;
    const int bm = (bid >> 3) * 128;
    const int bn = (bid & 7) * 128;

    const int lane = tid & 63;
    const int wid  = tid >> 6;
    const int wr = (wid >> 1) * 64;
    const int wc = (wid & 1) * 64;
    const int lr = lane & 15;
    const int lk = lane >> 4;

    const int row0 = tid >> 3;
    const int sl0  = tid & 7;

    f32x4 acc[4][4];
#pragma unroll
    for (int i = 0; i < 4; ++i)
#pragma unroll
        for (int j = 0; j < 4; ++j)
            acc[i][j] = (f32x4){0.f, 0.f, 0.f, 0.f};

    float4 la[4][2], lb[4][2];

#define F_LOAD_A(T) do {                                                      \
    const int k0_ = (T) * 64;                                                 \
    const float* sA_ = (k0_ < 1024)                                           \
        ? (x + (size_t)bm * IN_STRIDE + k0_)                                  \
        : (h + (size_t)bm * IN_STRIDE + (k0_ - 1024));                        \
    _Pragma("unroll")                                                         \
    for (int i_ = 0; i_ < 4; ++i_) {                                          \
        const float* pa_ = sA_ + (size_t)(row0 + i_ * 32) * IN_STRIDE + sl0 * 8; \
        la[i_][0] = *(const float4*)(pa_);                                    \
        la[i_][1] = *(const float4*)(pa_ + 4);                                \
    }                                                                         \
} while (0)

#define F_LOAD_B(T) do {                                                      \
    const float* sB_ = W + (size_t)bn * K_GLOBAL + (T) * 64;                  \
    _Pragma("unroll")                                                         \
    for (int i_ = 0; i_ < 4; ++i_) {                                          \
        const float* pb_ = sB_ + (size_t)(row0 + i_ * 32) * K_GLOBAL + sl0 * 8; \
        lb[i_][0] = *(const float4*)(pb_);                                    \
        lb[i_][1] = *(const float4*)(pb_ + 4);                                \
    }                                                                         \
} while (0)

    F_LOAD_A(0);
    F_LOAD_B(0);

    for (int t = 0; t < FNT; ++t) {
        bf16_t* __restrict__ Ab = As[t & 1];
        bf16_t* __restrict__ Bb = Bs[t & 1];

#pragma unroll
        for (int i = 0; i < 4; ++i) {
            const int row = row0 + i * 32;
            const int ssl = sl0 ^ (row & 7);
            bf16x8 va;
            va[0] = (bf16_t)la[i][0].x; va[1] = (bf16_t)la[i][0].y;
            va[2] = (bf16_t)la[i][0].z; va[3] = (bf16_t)la[i][0].w;
            va[4] = (bf16_t)la[i][1].x; va[5] = (bf16_t)la[i][1].y;
            va[6] = (bf16_t)la[i][1].z; va[7] = (bf16_t)la[i][1].w;
            *(bf16x8*)(Ab + row * 64 + ssl * 8) = va;
        }
#pragma unroll
        for (int i = 0; i < 4; ++i) {
            const int row = row0 + i * 32;
            const int ssl = sl0 ^ (row & 7);
            bf16x8 vb;
            vb[0] = (bf16_t)lb[i][0].x; vb[1] = (bf16_t)lb[i][0].y;
            vb[2] = (bf16_t)lb[i][0].z; vb[3] = (bf16_t)lb[i][0].w;
            vb[4] = (bf16_t)lb[i][1].x; vb[5] = (bf16_t)lb[i][1].y;
            vb[6] = (bf16_t)lb[i][1].z; vb[7] = (bf16_t)lb[i][1].w;
            *(bf16x8*)(Bb + row * 64 + ssl * 8) = vb;
        }

        __syncthreads();

        if (t + 1 < FNT) F_LOAD_A(t + 1);

#pragma unroll
        for (int kk = 0; kk < 2; ++kk) {
            bf16x8 af[4], bfr[4];
#pragma unroll
            for (int mf = 0; mf < 4; ++mf) {
                const int row = wr + mf * 16 + lr;
                const int sl  = (kk * 4 + lk) ^ (row & 7);
                af[mf] = *(const bf16x8*)(Ab + row * 64 + sl * 8);
            }
#pragma unroll
            for (int nf = 0; nf < 4; ++nf) {
                const int row = wc + nf * 16 + lr;
                const int sl  = (kk * 4 + lk) ^ (row & 7);
                bfr[nf] = *(const bf16x8*)(Bb + row * 64 + sl * 8);
            }
#pragma unroll
            for (int mf = 0; mf < 4; ++mf)
#pragma unroll
                for (int nf = 0; nf < 4; ++nf)
                    acc[mf][nf] = __builtin_amdgcn_mfma_f32_16x16x32_bf16(
                        af[mf], bfr[nf], acc[mf][nf], 0, 0, 0);
        }

        if (t + 1 < FNT) F_LOAD_B(t + 1);
    }
#undef F_LOAD_A
#undef F_LOAD_B

    float bv[4];
#pragma unroll
    for (int nf = 0; nf < 4; ++nf)
        bv[nf] = bias[bn + wc + nf * 16 + lr];
#pragma unroll
    for (int mf = 0; mf < 4; ++mf) {
#pragma unroll
        for (int nf = 0; nf < 4; ++nf) {
            const int col = bn + wc + nf * 16 + lr;
#pragma unroll
            for (int r = 0; r < 4; ++r) {
                const int row = bm + wr + mf * 16 + lk * 4 + r;
                out[(size_t)row * N_GLOBAL + col] = fast_tanh(acc[mf][nf][r] + bv[nf]);
            }
        }
    }
}

extern "C" void kernel_launch(void* const* d_in, const int* in_sizes, int n_in,
                              void* d_out, int out_size, void* d_ws, size_t ws_size,
                              hipStream_t stream) {
    (void)in_sizes; (void)n_in; (void)out_size;
    const float* x = (const float*)d_in[0];
    const float* h = (const float*)d_in[1];
    const float* W = (const float*)d_in[2];
    const float* b = (const float*)d_in[3];
    float* out = (float*)d_out;

    const size_t need = ((size_t)M_GLOBAL + N_GLOBAL) * K_GLOBAL * sizeof(bf16_t);
    if (ws_size >= need) {
        bf16_t* XHb = (bf16_t*)d_ws;
        bf16_t* Wb  = XHb + (size_t)M_GLOBAL * K_GLOBAL;
        cvt_pass<<<2048, 256, 0, stream>>>(x, h, W, XHb, Wb);
        gemm_wt<<<256, 512, 0, stream>>>(XHb, Wb, b, out);
    } else {
        rnncell_fused<<<1024, 256, 0, stream>>>(x, h, W, b, out);
    }
}

// Round 16
// 99.349 us; speedup vs baseline: 1.0275x; 1.0275x over previous
//
#include <hip/hip_runtime.h>
#include <hip/hip_bf16.h>

// RNN cell: out[B,N] = tanh( concat(x,hidden)[B,K] @ W^T[K,N] + b[N] )
// M=16384, N=1024, K=2048, fp32 in/out.
// Pass 1: fp32->bf16 cvt+concat into ws.
// Pass 2 (r14): 256x256 whole-tile GEMM, 1024 threads = 16 waves (4M x 4N),
//   64x64 out/wave -> acc 64 regs, total ~120 <= 128 -> 16 waves/CU =
//   4 waves/SIMD (2x r13). Theory: r5/r9/r13 all ~91us @ MfmaUtil 31% with
//   2 waves/SIMD -- no pipe saturated, stalls uncovered. Doubling waves/SIMD
//   gives the scheduler independent work during lgkm waits (m114 mechanism).
//   Schedule kept from r13 (equal-best, simplest): stage(t+1) at tile top,
//   fence-free compute, VM0+raw-barrier at tile end only.
// (r14/r15 benches died at container-connection setup -- source never
//  reached hardware. Third submission, identical source.)

typedef __bf16 bf16_t;
typedef __bf16 bf16x8 __attribute__((ext_vector_type(8)));
typedef float  f32x4  __attribute__((ext_vector_type(4)));

#define M_GLOBAL 16384
#define N_GLOBAL 1024
#define K_GLOBAL 2048
#define IN_STRIDE 1024
#define NT 32

__device__ __forceinline__ float fast_tanh(float v) {
    float e = __expf(2.0f * v);
    return 1.0f - 2.0f * __builtin_amdgcn_rcpf(e + 1.0f);
}

// ---------------------------------------------------------------------------
// Pass 1: cvt + concat (~6.4 TB/s; L3-warm on replay).
// ---------------------------------------------------------------------------
#define XH_UNITS ((long long)M_GLOBAL * K_GLOBAL / 8)
#define W_UNITS  ((long long)N_GLOBAL * K_GLOBAL / 8)

__global__ __launch_bounds__(256)
void cvt_pass(const float* __restrict__ x, const float* __restrict__ h,
              const float* __restrict__ W,
              bf16_t* __restrict__ XHb, bf16_t* __restrict__ Wb)
{
    const long long total = XH_UNITS + W_UNITS;
    for (long long u = (long long)blockIdx.x * 256 + threadIdx.x; u < total;
         u += (long long)gridDim.x * 256) {
        const float* src;
        bf16_t* dst;
        if (u < XH_UNITS) {
            const long long e = u * 8;
            const int row = (int)(e >> 11);
            const int col = (int)(e & 2047);
            src = (col < 1024) ? (x + (long long)row * IN_STRIDE + col)
                               : (h + (long long)row * IN_STRIDE + (col - 1024));
            dst = XHb + e;
        } else {
            const long long e = (u - XH_UNITS) * 8;
            src = W + e;
            dst = Wb + e;
        }
        const float4 v0 = *(const float4*)src;
        const float4 v1 = *(const float4*)(src + 4);
        bf16x8 o;
        o[0] = (bf16_t)v0.x; o[1] = (bf16_t)v0.y;
        o[2] = (bf16_t)v0.z; o[3] = (bf16_t)v0.w;
        o[4] = (bf16_t)v1.x; o[5] = (bf16_t)v1.y;
        o[6] = (bf16_t)v1.z; o[7] = (bf16_t)v1.w;
        *(bf16x8*)dst = o;
    }
}

// ---------------------------------------------------------------------------
// Pass 2: 256x256 whole-tile GEMM, 16 waves of 64x64.
// LDS: 2 dbuf x {A0,A1,B0,B1} 128x64 halves = 128 KB (1 block/CU).
// Swizzle (0 conflicts, verified r7-r13): slot s of row r holds k-slot
// s^(r&7); applied on global SOURCE (gload_lds writes linearly) + ds_read.
// Staging: 64 chunks (4 parts x 16); wave w stages chunk w of each part
// (4 gload_lds16/wave/tile).
// Race audit (as r13): stage(t+1) at top of t; VM0 at end drains own loads;
// barrier after VM0 -> tile t+1 fully resident before first read. WAR: the
// buffer being staged was last read in tile t-1, closed by the t-1 barrier.
// ---------------------------------------------------------------------------
__device__ __forceinline__ void gload_lds16(const bf16_t* g, bf16_t* l) {
    __builtin_amdgcn_global_load_lds(
        (const __attribute__((address_space(1))) void*)g,
        (__attribute__((address_space(3))) void*)l, 16, 0, 0);
}

__global__ __launch_bounds__(1024)
void gemm_w16(const bf16_t* __restrict__ XHb, const bf16_t* __restrict__ Wb,
              const float* __restrict__ bias, float* __restrict__ out)
{
    __shared__ __align__(16) bf16_t lds[2 * 32768];   // 128 KB

    const int tid = threadIdx.x;
    // r13 XCD map (kept: FETCH 135->49 MB): 4 blocks sharing an A-panel land
    // on one XCD; B panels L2-resident.
    const int x = blockIdx.x & 7;
    const int g = blockIdx.x >> 3;
    const int bm = (x * 8 + (g & 7)) * 256;
    const int bn = (g >> 3) * 256;

    const int lane = tid & 63;
    const int wid  = tid >> 6;        // 0..15
    const int wm = wid >> 2;          // 0..3 (M quarter)
    const int wn = wid & 3;           // 0..3 (N quarter)
    const int lr = lane & 15;
    const int lk = lane >> 4;
    const int s7 = lr & 7;

    // staging: wave w covers rows w*8..w*8+7 of each part; lane covers row
    // srow, source col pre-swizzled (linear LDS dest, rule 21).
    const int srow = lane >> 3;
    const int scol = ((lane & 7) ^ srow) * 8;
    const bf16_t* aS = XHb + (size_t)(bm + wid * 8 + srow) * K_GLOBAL + scol;
    const bf16_t* bS = Wb  + (size_t)(bn + wid * 8 + srow) * K_GLOBAL + scol;

    // frag-read bases (elems): parts A0,A1,B0,B1 at part*8192 within dbuf.
    // A row = wm*64 + mf*16 + lr -> part wm>>1, within-part (wm&1)*64+...
    const int aRd = (wm >> 1) * 8192 + ((wm & 1) * 64 + lr) * 64;
    const int bRd = (2 + (wn >> 1)) * 8192 + ((wn & 1) * 64 + lr) * 64;

    f32x4 acc[4][4];
#pragma unroll
    for (int i = 0; i < 4; ++i)
#pragma unroll
        for (int j = 0; j < 4; ++j)
            acc[i][j] = (f32x4){0.f, 0.f, 0.f, 0.f};

    // full-tile stage: one 1KB chunk per part per wave (4 gloads/thread)
#define STAGE_FULL(T, D) {                                                    \
    _Pragma("unroll")                                                         \
    for (int p_ = 0; p_ < 4; ++p_) {                                          \
        const bf16_t* g_ = ((p_ < 2) ? aS : bS)                               \
            + (size_t)((p_ & 1) * 128) * K_GLOBAL + (T) * 64;                 \
        gload_lds16(g_, lds + (D) * 32768 + p_ * 8192 + wid * 512);           \
    }                                                                         \
}

#define BAR() { asm volatile("" ::: "memory");                                \
                __builtin_amdgcn_s_barrier();                                 \
                asm volatile("" ::: "memory"); }
#define VM0() asm volatile("s_waitcnt vmcnt(0)" ::: "memory")

    // prologue: stage T0 -> dbuf0
    STAGE_FULL(0, 0);
    VM0();
    BAR();

    for (int t = 0; t < NT; ++t) {
        const int dbo = (t & 1) * 32768;

        // next tile's stage at the TOP: drained at end-of-tile VM0,
        // thousands of cycles later -> latency fully hidden.
        if (t + 1 < NT) STAGE_FULL(t + 1, (t + 1) & 1);

        // fence-free compute: 16 ds_read_b128 + 32 MFMA per wave; compiler's
        // fine-grained lgkmcnt(N) interleaves; 4 waves/SIMD cover the waits.
        __builtin_amdgcn_s_setprio(1);
#pragma unroll
        for (int kk = 0; kk < 2; ++kk) {
            const int sl = ((kk * 4 + lk) ^ s7) * 8;
            bf16x8 bq[4];
#pragma unroll
            for (int nf = 0; nf < 4; ++nf)
                bq[nf] = *(const bf16x8*)(lds + dbo + bRd + nf * 1024 + sl);
#pragma unroll
            for (int mf = 0; mf < 4; ++mf) {
                bf16x8 af = *(const bf16x8*)(lds + dbo + aRd + mf * 1024 + sl);
#pragma unroll
                for (int nf = 0; nf < 4; ++nf)
                    acc[mf][nf] = __builtin_amdgcn_mfma_f32_16x16x32_bf16(
                        af, bq[nf], acc[mf][nf], 0, 0, 0);
            }
        }
        __builtin_amdgcn_s_setprio(0);

        if (t + 1 < NT) { VM0(); BAR(); }
    }

#undef STAGE_FULL
#undef BAR
#undef VM0

    // ---- epilogue: bias + tanh, fp32 store.
    // C/D layout: col = lane&15, row = (lane>>4)*4 + reg (verified r1-r13).
    float bv[4];
#pragma unroll
    for (int nf = 0; nf < 4; ++nf)
        bv[nf] = bias[bn + wn * 64 + nf * 16 + lr];
#pragma unroll
    for (int mf = 0; mf < 4; ++mf) {
#pragma unroll
        for (int nf = 0; nf < 4; ++nf) {
            const int col = bn + wn * 64 + nf * 16 + lr;
#pragma unroll
            for (int r = 0; r < 4; ++r) {
                const int row = bm + wm * 64 + mf * 16 + lk * 4 + r;
                out[(size_t)row * N_GLOBAL + col] = fast_tanh(acc[mf][nf][r] + bv[nf]);
            }
        }
    }
}

// ---------------------------------------------------------------------------
// Fallback (ws too small): round-3 verified fused kernel (~169 us).
// ---------------------------------------------------------------------------
#define FNT 32
__global__ __launch_bounds__(256, 2)
void rnncell_fused(const float* __restrict__ x, const float* __restrict__ h,
                   const float* __restrict__ W, const float* __restrict__ bias,
                   float* __restrict__ out)
{
    __shared__ __align__(16) bf16_t As[2][128 * 64];
    __shared__ __align__(16) bf16_t Bs[2][128 * 64];

    const int tid = threadIdx.x;
    const int bid = blockIdx.x;
    const int bm = (bid >> 3) * 128;
    const int bn = (bid & 7) * 128;

    const int lane = tid & 63;
    const int wid  = tid >> 6;
    const int wr = (wid >> 1) * 64;
    const int wc = (wid & 1) * 64;
    const int lr = lane & 15;
    const int lk = lane >> 4;

    const int row0 = tid >> 3;
    const int sl0  = tid & 7;

    f32x4 acc[4][4];
#pragma unroll
    for (int i = 0; i < 4; ++i)
#pragma unroll
        for (int j = 0; j < 4; ++j)
            acc[i][j] = (f32x4){0.f, 0.f, 0.f, 0.f};

    float4 la[4][2], lb[4][2];

#define F_LOAD_A(T) do {                                                      \
    const int k0_ = (T) * 64;                                                 \
    const float* sA_ = (k0_ < 1024)                                           \
        ? (x + (size_t)bm * IN_STRIDE + k0_)                                  \
        : (h + (size_t)bm * IN_STRIDE + (k0_ - 1024));                        \
    _Pragma("unroll")                                                         \
    for (int i_ = 0; i_ < 4; ++i_) {                                          \
        const float* pa_ = sA_ + (size_t)(row0 + i_ * 32) * IN_STRIDE + sl0 * 8; \
        la[i_][0] = *(const float4*)(pa_);                                    \
        la[i_][1] = *(const float4*)(pa_ + 4);                                \
    }                                                                         \
} while (0)

#define F_LOAD_B(T) do {                                                      \
    const float* sB_ = W + (size_t)bn * K_GLOBAL + (T) * 64;                  \
    _Pragma("unroll")                                                         \
    for (int i_ = 0; i_ < 4; ++i_) {                                          \
        const float* pb_ = sB_ + (size_t)(row0 + i_ * 32) * K_GLOBAL + sl0 * 8; \
        lb[i_][0] = *(const float4*)(pb_);                                    \
        lb[i_][1] = *(const float4*)(pb_ + 4);                                \
    }                                                                         \
} while (0)

    F_LOAD_A(0);
    F_LOAD_B(0);

    for (int t = 0; t < FNT; ++t) {
        bf16_t* __restrict__ Ab = As[t & 1];
        bf16_t* __restrict__ Bb = Bs[t & 1];

#pragma unroll
        for (int i = 0; i < 4; ++i) {
            const int row = row0 + i * 32;
            const int ssl = sl0 ^ (row & 7);
            bf16x8 va;
            va[0] = (bf16_t)la[i][0].x; va[1] = (bf16_t)la[i][0].y;
            va[2] = (bf16_t)la[i][0].z; va[3] = (bf16_t)la[i][0].w;
            va[4] = (bf16_t)la[i][1].x; va[5] = (bf16_t)la[i][1].y;
            va[6] = (bf16_t)la[i][1].z; va[7] = (bf16_t)la[i][1].w;
            *(bf16x8*)(Ab + row * 64 + ssl * 8) = va;
        }
#pragma unroll
        for (int i = 0; i < 4; ++i) {
            const int row = row0 + i * 32;
            const int ssl = sl0 ^ (row & 7);
            bf16x8 vb;
            vb[0] = (bf16_t)lb[i][0].x; vb[1] = (bf16_t)lb[i][0].y;
            vb[2] = (bf16_t)lb[i][0].z; vb[3] = (bf16_t)lb[i][0].w;
            vb[4] = (bf16_t)lb[i][1].x; vb[5] = (bf16_t)lb[i][1].y;
            vb[6] = (bf16_t)lb[i][1].z; vb[7] = (bf16_t)lb[i][1].w;
            *(bf16x8*)(Bb + row * 64 + ssl * 8) = vb;
        }

        __syncthreads();

        if (t + 1 < FNT) F_LOAD_A(t + 1);

#pragma unroll
        for (int kk = 0; kk < 2; ++kk) {
            bf16x8 af[4], bfr[4];
#pragma unroll
            for (int mf = 0; mf < 4; ++mf) {
                const int row = wr + mf * 16 + lr;
                const int sl  = (kk * 4 + lk) ^ (row & 7);
                af[mf] = *(const bf16x8*)(Ab + row * 64 + sl * 8);
            }
#pragma unroll
            for (int nf = 0; nf < 4; ++nf) {
                const int row = wc + nf * 16 + lr;
                const int sl  = (kk * 4 + lk) ^ (row & 7);
                bfr[nf] = *(const bf16x8*)(Bb + row * 64 + sl * 8);
            }
#pragma unroll
            for (int mf = 0; mf < 4; ++mf)
#pragma unroll
                for (int nf = 0; nf < 4; ++nf)
                    acc[mf][nf] = __builtin_amdgcn_mfma_f32_16x16x32_bf16(
                        af[mf], bfr[nf], acc[mf][nf], 0, 0, 0);
        }

        if (t + 1 < FNT) F_LOAD_B(t + 1);
    }
#undef F_LOAD_A
#undef F_LOAD_B

    float bv[4];
#pragma unroll
    for (int nf = 0; nf < 4; ++nf)
        bv[nf] = bias[bn + wc + nf * 16 + lr];
#pragma unroll
    for (int mf = 0; mf < 4; ++mf) {
#pragma unroll
        for (int nf = 0; nf < 4; ++nf) {
            const int col = bn + wc + nf * 16 + lr;
#pragma unroll
            for (int r = 0; r < 4; ++r) {
                const int row = bm + wr + mf * 16 + lk * 4 + r;
                out[(size_t)row * N_GLOBAL + col] = fast_tanh(acc[mf][nf][r] + bv[nf]);
            }
        }
    }
}

extern "C" void kernel_launch(void* const* d_in, const int* in_sizes, int n_in,
                              void* d_out, int out_size, void* d_ws, size_t ws_size,
                              hipStream_t stream) {
    (void)in_sizes; (void)n_in; (void)out_size;
    const float* x = (const float*)d_in[0];
    const float* h = (const float*)d_in[1];
    const float* W = (const float*)d_in[2];
    const float* b = (const float*)d_in[3];
    float* out = (float*)d_out;

    const size_t need = ((size_t)M_GLOBAL + N_GLOBAL) * K_GLOBAL * sizeof(bf16_t);
    if (ws_size >= need) {
        bf16_t* XHb = (bf16_t*)d_ws;
        bf16_t* Wb  = XHb + (size_t)M_GLOBAL * K_GLOBAL;
        cvt_pass<<<2048, 256, 0, stream>>>(x, h, W, XHb, Wb);
        gemm_w16<<<256, 1024, 0, stream>>>(XHb, Wb, b, out);
    } else {
        rnncell_fused<<<1024, 256, 0, stream>>>(x, h, W, b, out);
    }
}